// Round 6
// baseline (258.721 us; speedup 1.0000x reference)
//
#include <hip/hip_runtime.h>
#include <math.h>

#define N_NODES 50000
#define N_EDGES 600000
#define HID 128
#define FFN_HID 256
#define NEG_SLOPE 0.2f
#define LN_EPS 1e-5f
#define BKT 64            // bucket capacity per node; max degree ~30 for E/N=12 Poisson

typedef unsigned short u16;
typedef unsigned int u32;
typedef __attribute__((ext_vector_type(8))) short short8;
typedef __attribute__((ext_vector_type(4))) float floatx4;

__device__ __forceinline__ u16 f2bf(float x) {
    unsigned int u = __float_as_uint(x);
    unsigned int r = u + 0x7FFFu + ((u >> 16) & 1u);
    return (u16)(r >> 16);
}
__device__ __forceinline__ float bflo(u32 u) { return __uint_as_float(u << 16); }
__device__ __forceinline__ float bfhi(u32 u) { return __uint_as_float(u & 0xffff0000u); }
__device__ __forceinline__ u32 packbf(float lo, float hi) {
    return (u32)f2bf(lo) | ((u32)f2bf(hi) << 16);
}
// tanh-form GELU: max |delta| vs exact erf-GELU ~3e-4; output is bf16-rounded anyway.
__device__ __forceinline__ float gelu_fast(float v) {
    float u = 1.5957691216057308f * fmaf(0.044715f * v * v, v, v);
    return v / (1.0f + __expf(-u));
}

#define FF_TILES (N_NODES / 16)   // 3125, exact (no tails anywhere)

// ---------------- fused: edge bucket scatter + weight pre-swizzle ----------------
// blocks [0, 2344): scatter edges into per-dst buckets (u16 src ids)
// blocks [2344, 2728): swizzle Wsrc/Wdst/W1/W2 into MFMA B-fragment order
//   frag = (ng>>4)*(K/32) + (k>>5); lane = ((k>>3)&3)*16 + (ng&15); j = k&7

__global__ void scatter_prep(const int* __restrict__ src, const int* __restrict__ dst,
                             int* __restrict__ cursor, u16* __restrict__ ebkt,
                             const float* __restrict__ Wsrc, const float* __restrict__ Wdst,
                             const float* __restrict__ W1, const float* __restrict__ W2,
                             u16* __restrict__ B1, u16* __restrict__ B2, u16* __restrict__ B3) {
    int b = blockIdx.x;
    if (b < 2344) {
        int e = b * 256 + threadIdx.x;
        if (e < N_EDGES) {
            int d = dst[e];
            int slot = atomicAdd(&cursor[d], 1);
            if (slot < BKT) ebkt[(size_t)d * BKT + slot] = (u16)src[e];
        }
        return;
    }
    int t = (b - 2344) * 256 + threadIdx.x;
    const float* W; u16* out; int K, Nc, noff;
    if (t < 16384)       { W = Wsrc; out = B1; K = 128; Nc = 128; noff = 0; }
    else if (t < 32768)  { W = Wdst; out = B1; K = 128; Nc = 128; noff = 128; t -= 16384; }
    else if (t < 65536)  { W = W1;   out = B2; K = 128; Nc = 256; noff = 0;   t -= 32768; }
    else if (t < 98304)  { W = W2;   out = B3; K = 256; Nc = 128; noff = 0;   t -= 65536; }
    else return;
    int n = t % Nc, k = t / Nc;
    int ng = noff + n;
    int ksteps = K >> 5;
    int frag = (ng >> 4) * ksteps + (k >> 5);
    int lane = ((k >> 3) & 3) * 16 + (ng & 15);
    int j = k & 7;
    out[((size_t)frag * 64 + lane) * 8 + j] = f2bf(W[(size_t)k * Nc + n]);
}

// ---------------- GEMM1: fs | fd (both bf16) = h @ [Wsrc|Wdst] + bias ----------------
// ffn1-style: full 64KB B1 frag table staged to LDS once; each wave owns an
// independent 16-row tile across all 256 output cols; grid-stride over tiles.

__global__ __launch_bounds__(256) void gemm_fsfd_mfma(
    const float* __restrict__ h, const u16* __restrict__ Bsw,
    const float* __restrict__ bsrc, const float* __restrict__ bdst,
    u16* __restrict__ fsb, u16* __restrict__ fdb)
{
    __shared__ u16 bs[32768];   // 64KB: 16 ngroups x 4 ks x 64 lanes x 8
    for (int i = threadIdx.x; i < 4096; i += 256)
        *(uint4*)(bs + (size_t)i * 8) = *(const uint4*)(Bsw + (size_t)i * 8);
    __syncthreads();
    int wave = threadIdx.x >> 6, lane = threadIdx.x & 63;
    int lrow = lane & 15, lq = lane >> 4;
    float bias[16];
    #pragma unroll
    for (int nt = 0; nt < 16; nt++)
        bias[nt] = (nt < 8) ? bsrc[nt * 16 + lrow] : bdst[(nt - 8) * 16 + lrow];

    for (int tile = blockIdx.x * 4 + wave; tile < FF_TILES; tile += gridDim.x * 4) {
        int m0 = tile * 16;
        const float* hrow = h + (size_t)(m0 + lrow) * HID;
        floatx4 acc[16];
        #pragma unroll
        for (int nt = 0; nt < 16; nt++) acc[nt] = {0.f, 0.f, 0.f, 0.f};
        #pragma unroll
        for (int ks = 0; ks < 4; ks++) {
            float4 va = *(const float4*)(hrow + ks * 32 + lq * 8);
            float4 vb = *(const float4*)(hrow + ks * 32 + lq * 8 + 4);
            short8 a;
            a[0] = (short)f2bf(va.x); a[1] = (short)f2bf(va.y);
            a[2] = (short)f2bf(va.z); a[3] = (short)f2bf(va.w);
            a[4] = (short)f2bf(vb.x); a[5] = (short)f2bf(vb.y);
            a[6] = (short)f2bf(vb.z); a[7] = (short)f2bf(vb.w);
            #pragma unroll
            for (int nt = 0; nt < 16; nt++) {
                short8 bfr = *(const short8*)&bs[((nt * 4 + ks) * 64 + lane) * 8];
                acc[nt] = __builtin_amdgcn_mfma_f32_16x16x32_bf16(a, bfr, acc[nt], 0, 0, 0);
            }
        }
        #pragma unroll
        for (int nt = 0; nt < 16; nt++) {
            u16* outp = (nt < 8) ? fsb : fdb;
            int cg = (nt & 7) * 16 + lrow;
            #pragma unroll
            for (int r = 0; r < 4; r++) {
                int row = m0 + lq * 4 + r;
                outp[(size_t)row * HID + cg] = f2bf(acc[nt][r] + bias[nt]);
            }
        }
    }
}

// ---------------- aggregation + residual + LN1 ----------------
// fs, fd both gathered/streamed bf16; h/h1 f32 anchors. Emits h1 twice:
// f32 (FFN residual) + bf16 (FFN MFMA A-operand).

__global__ __launch_bounds__(256) void aggregate_kernel(
    const u16* __restrict__ fsb, const u16* __restrict__ fdb,
    const float* __restrict__ h, const float* __restrict__ attn,
    const int* __restrict__ counts, const u16* __restrict__ ebkt,
    const float* __restrict__ g1, const float* __restrict__ beta1,
    float* __restrict__ h1f, u16* __restrict__ h1b)
{
    int wave = threadIdx.x >> 6, lane = threadIdx.x & 63;
    int node = blockIdx.x * 4 + wave;
    if (node >= N_NODES) return;
    int grp = lane >> 4, fl = lane & 15;
    int f = fl * 8;

    uint4 ud = *(const uint4*)&fdb[(size_t)node * HID + f];
    float fdv[8] = { bflo(ud.x), bfhi(ud.x), bflo(ud.y), bfhi(ud.y),
                     bflo(ud.z), bfhi(ud.z), bflo(ud.w), bfhi(ud.w) };
    float4 aA = *(const float4*)&attn[f];
    float4 aB = *(const float4*)&attn[f + 4];
    float c1[8] = { 0.6f * aA.x, 0.6f * aA.y, 0.6f * aA.z, 0.6f * aA.w,
                    0.6f * aB.x, 0.6f * aB.y, 0.6f * aB.z, 0.6f * aB.w };
    float c2[8] = { 0.4f * aA.x, 0.4f * aA.y, 0.4f * aA.z, 0.4f * aA.w,
                    0.4f * aB.x, 0.4f * aB.y, 0.4f * aB.z, 0.4f * aB.w };

    int cnt = counts[node]; cnt = cnt < BKT ? cnt : BKT;
    const u16* brow = ebkt + (size_t)node * BKT;
    float acc[8] = {0.f, 0.f, 0.f, 0.f, 0.f, 0.f, 0.f, 0.f};
    float lsum = 0.f;

    auto body = [&](int e) {
        int s = (int)brow[e];
        uint4 u = *(const uint4*)&fsb[(size_t)s * HID + f];
        float x[8] = { bflo(u.x), bfhi(u.x), bflo(u.y), bfhi(u.y),
                       bflo(u.z), bfhi(u.z), bflo(u.w), bfhi(u.w) };
        float p = 0.f;
        #pragma unroll
        for (int i = 0; i < 8; i++) {
            float ei = x[i] + fdv[i];
            p = fmaf(c1[i], ei, p);
            p = fmaf(c2[i], fabsf(ei), p);
        }
        // head logit: sum over the 4 lanes of this head's quad
        p += __shfl_xor(p, 1); p += __shfl_xor(p, 2);
        float w = __expf(p);
        lsum += w;
        #pragma unroll
        for (int i = 0; i < 8; i++) acc[i] = fmaf(w, x[i], acc[i]);
    };

    int e = grp;
    for (; e + 4 < cnt; e += 8) { body(e); body(e + 4); }
    if (e < cnt) body(e);

    // merge the 4 edge-groups (same features, same head per quad)
    #pragma unroll
    for (int i = 0; i < 8; i++) {
        acc[i] += __shfl_xor(acc[i], 16);
        acc[i] += __shfl_xor(acc[i], 32);
    }
    lsum += __shfl_xor(lsum, 16); lsum += __shfl_xor(lsum, 32);

    float inv = (lsum > 0.f) ? (1.0f / lsum) : 0.f;
    float4 h0 = *(const float4*)&h[(size_t)node * HID + f];
    float4 h1v = *(const float4*)&h[(size_t)node * HID + f + 4];
    float hx[8] = { h0.x, h0.y, h0.z, h0.w, h1v.x, h1v.y, h1v.z, h1v.w };
    float o[8], s1 = 0.f, s2 = 0.f;
    #pragma unroll
    for (int i = 0; i < 8; i++) {
        o[i] = hx[i] + acc[i] * inv;
        s1 += o[i]; s2 += o[i] * o[i];
    }
    s1 += __shfl_xor(s1, 1); s2 += __shfl_xor(s2, 1);
    s1 += __shfl_xor(s1, 2); s2 += __shfl_xor(s2, 2);
    s1 += __shfl_xor(s1, 4); s2 += __shfl_xor(s2, 4);
    s1 += __shfl_xor(s1, 8); s2 += __shfl_xor(s2, 8);
    float mu = s1 * (1.0f / HID);
    float var = s2 * (1.0f / HID) - mu * mu;
    float rs = rsqrtf(var + LN_EPS);
    if (grp == 0) {
        float4 gA = *(const float4*)&g1[f], gB = *(const float4*)&g1[f + 4];
        float4 bA = *(const float4*)&beta1[f], bB = *(const float4*)&beta1[f + 4];
        float q0 = (o[0] - mu) * rs * gA.x + bA.x, q1 = (o[1] - mu) * rs * gA.y + bA.y;
        float q2 = (o[2] - mu) * rs * gA.z + bA.z, q3 = (o[3] - mu) * rs * gA.w + bA.w;
        float q4 = (o[4] - mu) * rs * gB.x + bB.x, q5 = (o[5] - mu) * rs * gB.y + bB.y;
        float q6 = (o[6] - mu) * rs * gB.z + bB.z, q7 = (o[7] - mu) * rs * gB.w + bB.w;
        *(float4*)&h1f[(size_t)node * HID + f]     = make_float4(q0, q1, q2, q3);
        *(float4*)&h1f[(size_t)node * HID + f + 4] = make_float4(q4, q5, q6, q7);
        uint4 ob;
        ob.x = packbf(q0, q1); ob.y = packbf(q2, q3);
        ob.z = packbf(q4, q5); ob.w = packbf(q6, q7);
        *(uint4*)&h1b[(size_t)node * HID + f] = ob;
    }
}

// ---------------- FFN, two barrier-free GEMM kernels ----------------
// ffn1: t = gelu(h1 @ W1 + bf1)  (bf16, row-major, 50000x256)
// ffn2: out = LN(h1 + t @ W2 + bf2)
// Full 64KB frag table in LDS (one barrier), each wave owns independent
// 16-row tiles, grid-stride.

__global__ __launch_bounds__(256) void ffn1_kernel(
    const u16* __restrict__ h1b, const u16* __restrict__ B2sw,
    const float* __restrict__ bf1, u16* __restrict__ tbuf)
{
    __shared__ u16 bs[32768];
    for (int i = threadIdx.x; i < 4096; i += 256)
        *(uint4*)(bs + (size_t)i * 8) = *(const uint4*)(B2sw + (size_t)i * 8);
    __syncthreads();
    int wave = threadIdx.x >> 6, lane = threadIdx.x & 63;
    int lrow = lane & 15, lq = lane >> 4;
    float bias[16];
    #pragma unroll
    for (int nt = 0; nt < 16; nt++) bias[nt] = bf1[nt * 16 + lrow];

    for (int tile = blockIdx.x * 4 + wave; tile < FF_TILES; tile += gridDim.x * 4) {
        int m0 = tile * 16;
        floatx4 acc[16];
        #pragma unroll
        for (int nt = 0; nt < 16; nt++) acc[nt] = {0.f, 0.f, 0.f, 0.f};
        #pragma unroll
        for (int ks = 0; ks < 4; ks++) {
            short8 a = *(const short8*)(h1b + (size_t)(m0 + lrow) * HID + ks * 32 + lq * 8);
            #pragma unroll
            for (int nt = 0; nt < 16; nt++) {
                short8 b = *(const short8*)&bs[((nt * 4 + ks) * 64 + lane) * 8];
                acc[nt] = __builtin_amdgcn_mfma_f32_16x16x32_bf16(a, b, acc[nt], 0, 0, 0);
            }
        }
        #pragma unroll
        for (int nt = 0; nt < 16; nt++) {
            #pragma unroll
            for (int r = 0; r < 4; r++) {
                float v = acc[nt][r] + bias[nt];
                tbuf[(size_t)(m0 + lq * 4 + r) * FFN_HID + nt * 16 + lrow] = f2bf(gelu_fast(v));
            }
        }
    }
}

__global__ __launch_bounds__(256) void ffn2_kernel(
    const u16* __restrict__ tbuf, const float* __restrict__ h1f,
    const u16* __restrict__ B3sw, const float* __restrict__ bf2,
    const float* __restrict__ g2, const float* __restrict__ beta2,
    float* __restrict__ out)
{
    __shared__ u16 bs[32768];
    for (int i = threadIdx.x; i < 4096; i += 256)
        *(uint4*)(bs + (size_t)i * 8) = *(const uint4*)(B3sw + (size_t)i * 8);
    __syncthreads();
    int wave = threadIdx.x >> 6, lane = threadIdx.x & 63;
    int lrow = lane & 15, lq = lane >> 4;
    float bias2[8], g2v[8], be2v[8];
    #pragma unroll
    for (int nt = 0; nt < 8; nt++) {
        int cg = nt * 16 + lrow;
        bias2[nt] = bf2[cg]; g2v[nt] = g2[cg]; be2v[nt] = beta2[cg];
    }

    for (int tile = blockIdx.x * 4 + wave; tile < FF_TILES; tile += gridDim.x * 4) {
        int m0 = tile * 16;
        floatx4 acc[8];
        #pragma unroll
        for (int nt = 0; nt < 8; nt++) acc[nt] = {0.f, 0.f, 0.f, 0.f};
        #pragma unroll
        for (int ks = 0; ks < 8; ks++) {
            short8 a = *(const short8*)(tbuf + (size_t)(m0 + lrow) * FFN_HID + ks * 32 + lq * 8);
            #pragma unroll
            for (int nt = 0; nt < 8; nt++) {
                short8 b = *(const short8*)&bs[((nt * 8 + ks) * 64 + lane) * 8];
                acc[nt] = __builtin_amdgcn_mfma_f32_16x16x32_bf16(a, b, acc[nt], 0, 0, 0);
            }
        }
        // bias + f32 residual
        float xv[8][4];
        #pragma unroll
        for (int nt = 0; nt < 8; nt++) {
            #pragma unroll
            for (int r = 0; r < 4; r++) {
                int row = m0 + lq * 4 + r;
                xv[nt][r] = acc[nt][r] + bias2[nt] + h1f[(size_t)row * HID + nt * 16 + lrow];
            }
        }
        // wave-local LN per row (reduce over the 16-lane group)
        #pragma unroll
        for (int r = 0; r < 4; r++) {
            float s1 = 0.f, s2 = 0.f;
            #pragma unroll
            for (int nt = 0; nt < 8; nt++) { s1 += xv[nt][r]; s2 += xv[nt][r] * xv[nt][r]; }
            s1 += __shfl_xor(s1, 1); s2 += __shfl_xor(s2, 1);
            s1 += __shfl_xor(s1, 2); s2 += __shfl_xor(s2, 2);
            s1 += __shfl_xor(s1, 4); s2 += __shfl_xor(s2, 4);
            s1 += __shfl_xor(s1, 8); s2 += __shfl_xor(s2, 8);
            float mu = s1 * (1.0f / HID);
            float var = s2 * (1.0f / HID) - mu * mu;
            float rstd = rsqrtf(var + LN_EPS);
            int row = m0 + lq * 4 + r;
            #pragma unroll
            for (int nt = 0; nt < 8; nt++) {
                int cg = nt * 16 + lrow;
                out[(size_t)row * HID + cg] = (xv[nt][r] - mu) * rstd * g2v[nt] + be2v[nt];
            }
        }
    }
}

// ---------------- launch ----------------

extern "C" void kernel_launch(void* const* d_in, const int* in_sizes, int n_in,
                              void* d_out, int out_size, void* d_ws, size_t ws_size,
                              hipStream_t stream)
{
    const float* h    = (const float*)d_in[0];
    const int*   src  = (const int*)d_in[1];
    const int*   dst  = (const int*)d_in[2];
    const float* Wsrc = (const float*)d_in[3];
    const float* bsrc = (const float*)d_in[4];
    const float* Wdst = (const float*)d_in[5];
    const float* bdst = (const float*)d_in[6];
    const float* attn = (const float*)d_in[7];
    const float* W1   = (const float*)d_in[8];
    const float* bf1  = (const float*)d_in[9];
    const float* W2   = (const float*)d_in[10];
    const float* bf2  = (const float*)d_in[11];
    const float* g1   = (const float*)d_in[12];
    const float* beta1= (const float*)d_in[13];
    const float* g2   = (const float*)d_in[14];
    const float* beta2= (const float*)d_in[15];
    float* out = (float*)d_out;

    // workspace: fsb+fdb bf16 (12.8MB each, contiguous), h1f f32 (25.6MB),
    // h1b bf16 (12.8MB), B1/B2/B3 (64KB each), cursor (200KB), ebkt u16 (6.4MB).
    // tbuf (25.6MB) ALIASES fsb+fdb (dead after aggregate). ~71MB total.
    u16* fsb = (u16*)d_ws;
    u16* fdb = fsb + (size_t)N_NODES * HID;
    float* h1f = (float*)(fdb + (size_t)N_NODES * HID);
    u16* h1b = (u16*)(h1f + (size_t)N_NODES * HID);
    u16* B1 = h1b + (size_t)N_NODES * HID;
    u16* B2 = B1 + 32768;
    u16* B3 = B2 + 32768;
    int* cursor = (int*)(B3 + 32768);
    u16* ebkt   = (u16*)(cursor + N_NODES);
    u16* tbuf   = fsb;   // alias

    hipMemsetAsync(cursor, 0, N_NODES * sizeof(int), stream);
    scatter_prep<<<2728, 256, 0, stream>>>(src, dst, cursor, ebkt,
                                           Wsrc, Wdst, W1, W2, B1, B2, B3);
    gemm_fsfd_mfma<<<391, 256, 0, stream>>>(h, B1, bsrc, bdst, fsb, fdb);
    aggregate_kernel<<<(N_NODES + 3) / 4, 256, 0, stream>>>(fsb, fdb, h, attn, cursor, ebkt, g1, beta1, h1f, h1b);
    ffn1_kernel<<<391, 256, 0, stream>>>(h1b, B2, bf1, tbuf);
    ffn2_kernel<<<391, 256, 0, stream>>>(tbuf, h1f, B3, bf2, g2, beta2, out);
}

// Round 7
// 232.448 us; speedup vs baseline: 1.1130x; 1.1130x over previous
//
#include <hip/hip_runtime.h>
#include <math.h>

#define N_NODES 50000
#define N_EDGES 600000
#define HID 128
#define FFN_HID 256
#define NEG_SLOPE 0.2f
#define LN_EPS 1e-5f
#define BKT 64            // bucket capacity per node; max degree ~30 for E/N=12 Poisson
#define CSTR 16           // cursor stride (ints): one counter per 64B line

typedef unsigned short u16;
typedef unsigned int u32;
typedef __attribute__((ext_vector_type(8))) short short8;
typedef __attribute__((ext_vector_type(4))) float floatx4;

__device__ __forceinline__ u16 f2bf(float x) {
    unsigned int u = __float_as_uint(x);
    unsigned int r = u + 0x7FFFu + ((u >> 16) & 1u);
    return (u16)(r >> 16);
}
__device__ __forceinline__ float bflo(u32 u) { return __uint_as_float(u << 16); }
__device__ __forceinline__ float bfhi(u32 u) { return __uint_as_float(u & 0xffff0000u); }
__device__ __forceinline__ u32 packbf(float lo, float hi) {
    return (u32)f2bf(lo) | ((u32)f2bf(hi) << 16);
}
__device__ __forceinline__ float bf2f(u16 v) { return __uint_as_float(((u32)v) << 16); }
// tanh-form GELU: max |delta| vs exact erf-GELU ~3e-4; output is bf16-rounded anyway.
__device__ __forceinline__ float gelu_fast(float v) {
    float u = 1.5957691216057308f * fmaf(0.044715f * v * v, v, v);
    return v / (1.0f + __expf(-u));
}

// ---------------- weight pre-swizzle (Wsrc/Wdst/W1/W2 -> MFMA B-fragment order) ----
//   frag = (ng>>4)*(K/32) + (k>>5); lane = ((k>>3)&3)*16 + (ng&15); j = k&7

__global__ __launch_bounds__(256) void swizzle_prep(
    const float* __restrict__ Wsrc, const float* __restrict__ Wdst,
    const float* __restrict__ W1, const float* __restrict__ W2,
    u16* __restrict__ B1, u16* __restrict__ B2, u16* __restrict__ B3)
{
    int t = blockIdx.x * 256 + threadIdx.x;
    const float* W; u16* out; int K, Nc, noff;
    if (t < 16384)       { W = Wsrc; out = B1; K = 128; Nc = 128; noff = 0; }
    else if (t < 32768)  { W = Wdst; out = B1; K = 128; Nc = 128; noff = 128; t -= 16384; }
    else if (t < 65536)  { W = W1;   out = B2; K = 128; Nc = 256; noff = 0;   t -= 32768; }
    else if (t < 98304)  { W = W2;   out = B3; K = 256; Nc = 128; noff = 0;   t -= 65536; }
    else return;
    int n = t % Nc, k = t / Nc;
    int ng = noff + n;
    int ksteps = K >> 5;
    int frag = (ng >> 4) * ksteps + (k >> 5);
    int lane = ((k >> 3) & 3) * 16 + (ng & 15);
    int j = k & 7;
    out[((size_t)frag * 64 + lane) * 8 + j] = f2bf(W[(size_t)k * Nc + n]);
}

// ---------------- co-launched: edge bucket scatter + GEMM1 ----------------
// blocks [0, 2344): scatter edges into per-dst buckets (u16 src ids);
//   atomic-bound, overlaps with the MFMA-bound gemm blocks on the same grid.
// blocks [2344, 2344+1024): fs | fd (both bf16) = h @ [Wsrc|Wdst] + bias.
//   Persistent B-fragments in registers (R3-proven structure), grid-stride.

__global__ __launch_bounds__(256) void scatter_gemm(
    const int* __restrict__ src, const int* __restrict__ dst,
    int* __restrict__ cursor, u16* __restrict__ ebkt,
    const float* __restrict__ h, const u16* __restrict__ Bsw,
    const float* __restrict__ bsrc, const float* __restrict__ bdst,
    u16* __restrict__ fsb, u16* __restrict__ fdb)
{
    if (blockIdx.x < 2344) {
        int e = blockIdx.x * 256 + threadIdx.x;
        if (e < N_EDGES) {
            int d = dst[e];
            int slot = atomicAdd(&cursor[d * CSTR], 1);
            if (slot < BKT) ebkt[(size_t)d * BKT + slot] = (u16)src[e];
        }
        return;
    }
    int bid = blockIdx.x - 2344;
    int tid = threadIdx.x, wave = tid >> 6, lane = tid & 63;
    int lrow = lane & 15, lq = lane >> 4;
    short8 bfrag[4][4];
    #pragma unroll
    for (int nt = 0; nt < 4; nt++)
        #pragma unroll
        for (int ks = 0; ks < 4; ks++) {
            int frag = (wave * 4 + nt) * 4 + ks;
            bfrag[nt][ks] = *(const short8*)(Bsw + ((size_t)frag * 64 + lane) * 8);
        }
    float bias[4];
    #pragma unroll
    for (int nt = 0; nt < 4; nt++) {
        int cg = wave * 64 + nt * 16 + lrow;
        bias[nt] = (cg < HID) ? bsrc[cg] : bdst[cg - HID];
    }
    for (int mb = bid; mb < N_NODES / 16; mb += 1024) {
        int m0 = mb * 16;
        const float* hrow = h + (size_t)(m0 + lrow) * HID;
        floatx4 acc[4];
        #pragma unroll
        for (int nt = 0; nt < 4; nt++) acc[nt] = {0.f, 0.f, 0.f, 0.f};
        #pragma unroll
        for (int ks = 0; ks < 4; ks++) {
            float4 va = *(const float4*)(hrow + ks * 32 + lq * 8);
            float4 vb = *(const float4*)(hrow + ks * 32 + lq * 8 + 4);
            short8 a;
            a[0] = (short)f2bf(va.x); a[1] = (short)f2bf(va.y);
            a[2] = (short)f2bf(va.z); a[3] = (short)f2bf(va.w);
            a[4] = (short)f2bf(vb.x); a[5] = (short)f2bf(vb.y);
            a[6] = (short)f2bf(vb.z); a[7] = (short)f2bf(vb.w);
            #pragma unroll
            for (int nt = 0; nt < 4; nt++)
                acc[nt] = __builtin_amdgcn_mfma_f32_16x16x32_bf16(a, bfrag[nt][ks], acc[nt], 0, 0, 0);
        }
        #pragma unroll
        for (int nt = 0; nt < 4; nt++) {
            int cg = wave * 64 + nt * 16 + lrow;      // wave-uniform branch per (wave,nt)
            u16* outp = (cg < HID) ? fsb : fdb;
            int c = cg & (HID - 1);
            #pragma unroll
            for (int r = 0; r < 4; r++) {
                int row = m0 + lq * 4 + r;
                outp[(size_t)row * HID + c] = f2bf(acc[nt][r] + bias[nt]);
            }
        }
    }
}

// ---------------- aggregation + residual + LN1 ----------------
// fs, fd gathered/streamed bf16; h residual f32. Emits h1 ONCE, as bf16
// (h1b) — FFN uses it for both its MFMA A-operand and its residual.

__global__ __launch_bounds__(256) void aggregate_kernel(
    const u16* __restrict__ fsb, const u16* __restrict__ fdb,
    const float* __restrict__ h, const float* __restrict__ attn,
    const int* __restrict__ cursor, const u16* __restrict__ ebkt,
    const float* __restrict__ g1, const float* __restrict__ beta1,
    u16* __restrict__ h1b)
{
    int wave = threadIdx.x >> 6, lane = threadIdx.x & 63;
    int node = blockIdx.x * 4 + wave;
    if (node >= N_NODES) return;
    int grp = lane >> 4, fl = lane & 15;
    int f = fl * 8;

    uint4 ud = *(const uint4*)&fdb[(size_t)node * HID + f];
    float fdv[8] = { bflo(ud.x), bfhi(ud.x), bflo(ud.y), bfhi(ud.y),
                     bflo(ud.z), bfhi(ud.z), bflo(ud.w), bfhi(ud.w) };
    float4 aA = *(const float4*)&attn[f];
    float4 aB = *(const float4*)&attn[f + 4];
    float c1[8] = { 0.6f * aA.x, 0.6f * aA.y, 0.6f * aA.z, 0.6f * aA.w,
                    0.6f * aB.x, 0.6f * aB.y, 0.6f * aB.z, 0.6f * aB.w };
    float c2[8] = { 0.4f * aA.x, 0.4f * aA.y, 0.4f * aA.z, 0.4f * aA.w,
                    0.4f * aB.x, 0.4f * aB.y, 0.4f * aB.z, 0.4f * aB.w };

    int cnt = cursor[node * CSTR]; cnt = cnt < BKT ? cnt : BKT;
    const u16* brow = ebkt + (size_t)node * BKT;
    float acc[8] = {0.f, 0.f, 0.f, 0.f, 0.f, 0.f, 0.f, 0.f};
    float lsum = 0.f;

    auto body = [&](int e) {
        int s = (int)brow[e];
        uint4 u = *(const uint4*)&fsb[(size_t)s * HID + f];
        float x[8] = { bflo(u.x), bfhi(u.x), bflo(u.y), bfhi(u.y),
                       bflo(u.z), bfhi(u.z), bflo(u.w), bfhi(u.w) };
        float p = 0.f;
        #pragma unroll
        for (int i = 0; i < 8; i++) {
            float ei = x[i] + fdv[i];
            p = fmaf(c1[i], ei, p);
            p = fmaf(c2[i], fabsf(ei), p);
        }
        // head logit: sum over the 4 lanes of this head's quad
        p += __shfl_xor(p, 1); p += __shfl_xor(p, 2);
        float w = __expf(p);
        lsum += w;
        #pragma unroll
        for (int i = 0; i < 8; i++) acc[i] = fmaf(w, x[i], acc[i]);
    };

    int e = grp;
    for (; e + 4 < cnt; e += 8) { body(e); body(e + 4); }
    if (e < cnt) body(e);

    // merge the 4 edge-groups (same features, same head per quad)
    #pragma unroll
    for (int i = 0; i < 8; i++) {
        acc[i] += __shfl_xor(acc[i], 16);
        acc[i] += __shfl_xor(acc[i], 32);
    }
    lsum += __shfl_xor(lsum, 16); lsum += __shfl_xor(lsum, 32);

    float inv = (lsum > 0.f) ? (1.0f / lsum) : 0.f;
    float4 h0 = *(const float4*)&h[(size_t)node * HID + f];
    float4 h1v = *(const float4*)&h[(size_t)node * HID + f + 4];
    float hx[8] = { h0.x, h0.y, h0.z, h0.w, h1v.x, h1v.y, h1v.z, h1v.w };
    float o[8], s1 = 0.f, s2 = 0.f;
    #pragma unroll
    for (int i = 0; i < 8; i++) {
        o[i] = hx[i] + acc[i] * inv;
        s1 += o[i]; s2 += o[i] * o[i];
    }
    s1 += __shfl_xor(s1, 1); s2 += __shfl_xor(s2, 1);
    s1 += __shfl_xor(s1, 2); s2 += __shfl_xor(s2, 2);
    s1 += __shfl_xor(s1, 4); s2 += __shfl_xor(s2, 4);
    s1 += __shfl_xor(s1, 8); s2 += __shfl_xor(s2, 8);
    float mu = s1 * (1.0f / HID);
    float var = s2 * (1.0f / HID) - mu * mu;
    float rs = rsqrtf(var + LN_EPS);
    if (grp == 0) {
        float4 gA = *(const float4*)&g1[f], gB = *(const float4*)&g1[f + 4];
        float4 bA = *(const float4*)&beta1[f], bB = *(const float4*)&beta1[f + 4];
        float q0 = (o[0] - mu) * rs * gA.x + bA.x, q1 = (o[1] - mu) * rs * gA.y + bA.y;
        float q2 = (o[2] - mu) * rs * gA.z + bA.z, q3 = (o[3] - mu) * rs * gA.w + bA.w;
        float q4 = (o[4] - mu) * rs * gB.x + bB.x, q5 = (o[5] - mu) * rs * gB.y + bB.y;
        float q6 = (o[6] - mu) * rs * gB.z + bB.z, q7 = (o[7] - mu) * rs * gB.w + bB.w;
        uint4 ob;
        ob.x = packbf(q0, q1); ob.y = packbf(q2, q3);
        ob.z = packbf(q4, q5); ob.w = packbf(q6, q7);
        *(uint4*)&h1b[(size_t)node * HID + f] = ob;
    }
}

// ---------------- fused FFN: out = LN(h1 + gelu(h1@W1+bf1)@W2 + bf2) ----------------
// R3-proven M=16 structure at 640 blocks; A-operand AND residual from bf16 h1b.

#define TS_PAD 8   // +8 u16 = 16B: breaks 512B-stride bank pattern on phase-2 ds_read_b128

__global__ __launch_bounds__(256) void ffn_fused(
    const u16* __restrict__ h1b,
    const u16* __restrict__ B2sw, const u16* __restrict__ B3sw,
    const float* __restrict__ bf1, const float* __restrict__ bf2,
    const float* __restrict__ g2, const float* __restrict__ beta2,
    float* __restrict__ out)
{
    __shared__ u16 ts[16][FFN_HID + TS_PAD];
    __shared__ float xs[16][HID];
    int tid = threadIdx.x, wave = tid >> 6, lane = tid & 63;
    int lrow = lane & 15, lq = lane >> 4;

    short8 b1f[4][4];
    #pragma unroll
    for (int nt = 0; nt < 4; nt++)
        #pragma unroll
        for (int ks = 0; ks < 4; ks++) {
            int frag = (wave * 4 + nt) * 4 + ks;
            b1f[nt][ks] = *(const short8*)(B2sw + ((size_t)frag * 64 + lane) * 8);
        }
    short8 b2f[2][8];
    #pragma unroll
    for (int nt = 0; nt < 2; nt++)
        #pragma unroll
        for (int ks = 0; ks < 8; ks++) {
            int frag = (wave * 2 + nt) * 8 + ks;
            b2f[nt][ks] = *(const short8*)(B3sw + ((size_t)frag * 64 + lane) * 8);
        }
    float bias1[4];
    #pragma unroll
    for (int nt = 0; nt < 4; nt++) bias1[nt] = bf1[wave * 64 + nt * 16 + lrow];
    float bias2[2];
    #pragma unroll
    for (int nt = 0; nt < 2; nt++) bias2[nt] = bf2[wave * 32 + nt * 16 + lrow];

    for (int mb = blockIdx.x; mb < N_NODES / 16; mb += gridDim.x) {
        int m0 = mb * 16;
        // ---- phase 1: t = gelu(h1 @ W1 + bf1) into LDS ----
        floatx4 acc1[4];
        #pragma unroll
        for (int nt = 0; nt < 4; nt++) acc1[nt] = {0.f, 0.f, 0.f, 0.f};
        #pragma unroll
        for (int ks = 0; ks < 4; ks++) {
            short8 a = *(const short8*)(h1b + (size_t)(m0 + lrow) * HID + ks * 32 + lq * 8);
            #pragma unroll
            for (int nt = 0; nt < 4; nt++)
                acc1[nt] = __builtin_amdgcn_mfma_f32_16x16x32_bf16(a, b1f[nt][ks], acc1[nt], 0, 0, 0);
        }
        #pragma unroll
        for (int nt = 0; nt < 4; nt++) {
            int cg = wave * 64 + nt * 16 + lrow;
            #pragma unroll
            for (int r = 0; r < 4; r++) {
                float v = acc1[nt][r] + bias1[nt];
                ts[lq * 4 + r][cg] = f2bf(gelu_fast(v));
            }
        }
        __syncthreads();
        // ---- phase 2: x = t @ W2 + bf2 + h1 (residual from bf16 h1b) ----
        floatx4 acc2[2];
        #pragma unroll
        for (int nt = 0; nt < 2; nt++) acc2[nt] = {0.f, 0.f, 0.f, 0.f};
        #pragma unroll
        for (int ks = 0; ks < 8; ks++) {
            short8 a = *(const short8*)&ts[lrow][ks * 32 + lq * 8];
            #pragma unroll
            for (int nt = 0; nt < 2; nt++)
                acc2[nt] = __builtin_amdgcn_mfma_f32_16x16x32_bf16(a, b2f[nt][ks], acc2[nt], 0, 0, 0);
        }
        #pragma unroll
        for (int nt = 0; nt < 2; nt++) {
            int cg = wave * 32 + nt * 16 + lrow;
            #pragma unroll
            for (int r = 0; r < 4; r++) {
                int row = m0 + lq * 4 + r;
                float resid = bf2f(h1b[(size_t)row * HID + cg]);
                xs[lq * 4 + r][cg] = acc2[nt][r] + bias2[nt] + resid;
            }
        }
        __syncthreads();
        // ---- LN + store ----
        int row = tid >> 4, c0 = (tid & 15) * 8;
        float v[8];
        float s1 = 0.f, s2 = 0.f;
        #pragma unroll
        for (int i = 0; i < 8; i++) { v[i] = xs[row][c0 + i]; s1 += v[i]; s2 += v[i] * v[i]; }
        s1 += __shfl_xor(s1, 1); s2 += __shfl_xor(s2, 1);
        s1 += __shfl_xor(s1, 2); s2 += __shfl_xor(s2, 2);
        s1 += __shfl_xor(s1, 4); s2 += __shfl_xor(s2, 4);
        s1 += __shfl_xor(s1, 8); s2 += __shfl_xor(s2, 8);
        float mu = s1 * (1.0f / HID);
        float var = s2 * (1.0f / HID) - mu * mu;
        float rs = rsqrtf(var + LN_EPS);
        float o[8];
        #pragma unroll
        for (int i = 0; i < 8; i++) o[i] = (v[i] - mu) * rs * g2[c0 + i] + beta2[c0 + i];
        float* op = out + (size_t)(m0 + row) * HID + c0;
        *(float4*)(op)     = make_float4(o[0], o[1], o[2], o[3]);
        *(float4*)(op + 4) = make_float4(o[4], o[5], o[6], o[7]);
        __syncthreads();
    }
}

// ---------------- launch ----------------

extern "C" void kernel_launch(void* const* d_in, const int* in_sizes, int n_in,
                              void* d_out, int out_size, void* d_ws, size_t ws_size,
                              hipStream_t stream)
{
    const float* h    = (const float*)d_in[0];
    const int*   src  = (const int*)d_in[1];
    const int*   dst  = (const int*)d_in[2];
    const float* Wsrc = (const float*)d_in[3];
    const float* bsrc = (const float*)d_in[4];
    const float* Wdst = (const float*)d_in[5];
    const float* bdst = (const float*)d_in[6];
    const float* attn = (const float*)d_in[7];
    const float* W1   = (const float*)d_in[8];
    const float* bf1  = (const float*)d_in[9];
    const float* W2   = (const float*)d_in[10];
    const float* bf2  = (const float*)d_in[11];
    const float* g1   = (const float*)d_in[12];
    const float* beta1= (const float*)d_in[13];
    const float* g2   = (const float*)d_in[14];
    const float* beta2= (const float*)d_in[15];
    float* out = (float*)d_out;

    // workspace: fsb/fdb/h1b bf16 (12.8MB each), B1/B2/B3 (64KB each),
    // cursor (3.2MB, 64B-strided counters), ebkt u16 (6.4MB). ~49MB total.
    u16* fsb = (u16*)d_ws;
    u16* fdb = fsb + (size_t)N_NODES * HID;
    u16* h1b = fdb + (size_t)N_NODES * HID;
    u16* B1 = h1b + (size_t)N_NODES * HID;
    u16* B2 = B1 + 32768;
    u16* B3 = B2 + 32768;
    int* cursor = (int*)(B3 + 32768);
    u16* ebkt   = (u16*)(cursor + (size_t)N_NODES * CSTR);

    hipMemsetAsync(cursor, 0, (size_t)N_NODES * CSTR * sizeof(int), stream);
    swizzle_prep<<<384, 256, 0, stream>>>(Wsrc, Wdst, W1, W2, B1, B2, B3);
    scatter_gemm<<<2344 + 1024, 256, 0, stream>>>(src, dst, cursor, ebkt,
                                                  h, B1, bsrc, bdst, fsb, fdb);
    aggregate_kernel<<<(N_NODES + 3) / 4, 256, 0, stream>>>(fsb, fdb, h, attn, cursor, ebkt, g1, beta1, h1b);
    ffn_fused<<<640, 256, 0, stream>>>(h1b, B2, B3, bf1, bf2, g2, beta2, out);
}

// Round 8
// 221.558 us; speedup vs baseline: 1.1677x; 1.0491x over previous
//
#include <hip/hip_runtime.h>
#include <math.h>

#define N_NODES 50000
#define N_EDGES 600000
#define HID 128
#define FFN_HID 256
#define NEG_SLOPE 0.2f
#define LN_EPS 1e-5f
#define BKT 64            // bucket capacity per node; max degree ~30 for E/N=12 Poisson
#define CSTR 16           // cursor stride (ints): one counter per 64B line

typedef unsigned short u16;
typedef unsigned int u32;
typedef __attribute__((ext_vector_type(8))) short short8;
typedef __attribute__((ext_vector_type(4))) float floatx4;

__device__ __forceinline__ u16 f2bf(float x) {
    unsigned int u = __float_as_uint(x);
    unsigned int r = u + 0x7FFFu + ((u >> 16) & 1u);
    return (u16)(r >> 16);
}
__device__ __forceinline__ float bflo(u32 u) { return __uint_as_float(u << 16); }
__device__ __forceinline__ float bfhi(u32 u) { return __uint_as_float(u & 0xffff0000u); }
__device__ __forceinline__ u32 packbf(float lo, float hi) {
    return (u32)f2bf(lo) | ((u32)f2bf(hi) << 16);
}
__device__ __forceinline__ float bf2f(u16 v) { return __uint_as_float(((u32)v) << 16); }
// tanh-form GELU: max |delta| vs exact erf-GELU ~3e-4; output is bf16-rounded anyway.
__device__ __forceinline__ float gelu_fast(float v) {
    float u = 1.5957691216057308f * fmaf(0.044715f * v * v, v, v);
    return v / (1.0f + __expf(-u));
}

// ---------------- prep: weight swizzle + cursor zero (one kernel) ----------------
// blocks [0,384): swizzle Wsrc/Wdst/W1/W2 into MFMA B-fragment order
//   frag = (ng>>4)*(K/32) + (k>>5); lane = ((k>>3)&3)*16 + (ng&15); j = k&7
// blocks [384, 384+3125): zero the strided cursor array

__global__ __launch_bounds__(256) void prep_kernel(
    const float* __restrict__ Wsrc, const float* __restrict__ Wdst,
    const float* __restrict__ W1, const float* __restrict__ W2,
    u16* __restrict__ B1, u16* __restrict__ B2, u16* __restrict__ B3,
    int* __restrict__ cursor)
{
    int b = blockIdx.x;
    if (b >= 384) {
        int i = (b - 384) * 256 + threadIdx.x;
        if (i < N_NODES * CSTR) cursor[i] = 0;
        return;
    }
    int t = b * 256 + threadIdx.x;
    const float* W; u16* out; int K, Nc, noff;
    if (t < 16384)       { W = Wsrc; out = B1; K = 128; Nc = 128; noff = 0; }
    else if (t < 32768)  { W = Wdst; out = B1; K = 128; Nc = 128; noff = 128; t -= 16384; }
    else if (t < 65536)  { W = W1;   out = B2; K = 128; Nc = 256; noff = 0;   t -= 32768; }
    else if (t < 98304)  { W = W2;   out = B3; K = 256; Nc = 128; noff = 0;   t -= 65536; }
    else return;
    int n = t % Nc, k = t / Nc;
    int ng = noff + n;
    int ksteps = K >> 5;
    int frag = (ng >> 4) * ksteps + (k >> 5);
    int lane = ((k >> 3) & 3) * 16 + (ng & 15);
    int j = k & 7;
    out[((size_t)frag * 64 + lane) * 8 + j] = f2bf(W[(size_t)k * Nc + n]);
}

// ---------------- co-launched (INTERLEAVED): edge bucket scatter + GEMM1 ----------
// gemm role: bid%3==0 && bid<3072 (1024 blocks, gid=bid/3);
// scatter role: the remaining 2344 blocks (sid dense 0..2343).
// Interleaving keeps both roles co-resident on every CU from the first
// dispatch wave -> atomic latency hides under MFMA waves (m114 overlap).

__global__ __launch_bounds__(256) void scatter_gemm(
    const int* __restrict__ src, const int* __restrict__ dst,
    int* __restrict__ cursor, u16* __restrict__ ebkt,
    const float* __restrict__ h, const u16* __restrict__ Bsw,
    const float* __restrict__ bsrc, const float* __restrict__ bdst,
    u16* __restrict__ fsb, u16* __restrict__ fdb)
{
    int bid = blockIdx.x;
    bool isGemm = ((bid % 3) == 0) && (bid < 3072);
    if (!isGemm) {
        int g_lt = (bid + 2) / 3; g_lt = g_lt < 1024 ? g_lt : 1024;
        int sid = bid - g_lt;
        int e = sid * 256 + threadIdx.x;
        if (e < N_EDGES) {
            int d = dst[e];
            int slot = atomicAdd(&cursor[d * CSTR], 1);
            if (slot < BKT) ebkt[(size_t)d * BKT + slot] = (u16)src[e];
        }
        return;
    }
    int gid = bid / 3;
    int tid = threadIdx.x, wave = tid >> 6, lane = tid & 63;
    int lrow = lane & 15, lq = lane >> 4;
    short8 bfrag[4][4];
    #pragma unroll
    for (int nt = 0; nt < 4; nt++)
        #pragma unroll
        for (int ks = 0; ks < 4; ks++) {
            int frag = (wave * 4 + nt) * 4 + ks;
            bfrag[nt][ks] = *(const short8*)(Bsw + ((size_t)frag * 64 + lane) * 8);
        }
    float bias[4];
    #pragma unroll
    for (int nt = 0; nt < 4; nt++) {
        int cg = wave * 64 + nt * 16 + lrow;
        bias[nt] = (cg < HID) ? bsrc[cg] : bdst[cg - HID];
    }
    for (int mb = gid; mb < N_NODES / 16; mb += 1024) {
        int m0 = mb * 16;
        const float* hrow = h + (size_t)(m0 + lrow) * HID;
        floatx4 acc[4];
        #pragma unroll
        for (int nt = 0; nt < 4; nt++) acc[nt] = {0.f, 0.f, 0.f, 0.f};
        #pragma unroll
        for (int ks = 0; ks < 4; ks++) {
            float4 va = *(const float4*)(hrow + ks * 32 + lq * 8);
            float4 vb = *(const float4*)(hrow + ks * 32 + lq * 8 + 4);
            short8 a;
            a[0] = (short)f2bf(va.x); a[1] = (short)f2bf(va.y);
            a[2] = (short)f2bf(va.z); a[3] = (short)f2bf(va.w);
            a[4] = (short)f2bf(vb.x); a[5] = (short)f2bf(vb.y);
            a[6] = (short)f2bf(vb.z); a[7] = (short)f2bf(vb.w);
            #pragma unroll
            for (int nt = 0; nt < 4; nt++)
                acc[nt] = __builtin_amdgcn_mfma_f32_16x16x32_bf16(a, bfrag[nt][ks], acc[nt], 0, 0, 0);
        }
        #pragma unroll
        for (int nt = 0; nt < 4; nt++) {
            int cg = wave * 64 + nt * 16 + lrow;      // wave-uniform branch per (wave,nt)
            u16* outp = (cg < HID) ? fsb : fdb;
            int c = cg & (HID - 1);
            #pragma unroll
            for (int r = 0; r < 4; r++) {
                int row = m0 + lq * 4 + r;
                outp[(size_t)row * HID + c] = f2bf(acc[nt][r] + bias[nt]);
            }
        }
    }
}

// ---------------- aggregation + residual + LN1 ----------------
// fs, fd gathered/streamed bf16; h residual f32. Emits h1 ONCE as bf16.
// Gather loop is software-pipelined: 3-buffer rotation, the fsb row for
// edge e+8 is issued while computing edge e (depth-2 -> ~220cy tolerance
// per wave; x8 waves/SIMD covers the ~600cy L2/LLC gather latency).

__global__ __launch_bounds__(256) void aggregate_kernel(
    const u16* __restrict__ fsb, const u16* __restrict__ fdb,
    const float* __restrict__ h, const float* __restrict__ attn,
    const int* __restrict__ cursor, const u16* __restrict__ ebkt,
    const float* __restrict__ g1, const float* __restrict__ beta1,
    u16* __restrict__ h1b)
{
    int wave = threadIdx.x >> 6, lane = threadIdx.x & 63;
    int node = blockIdx.x * 4 + wave;
    if (node >= N_NODES) return;
    int grp = lane >> 4, fl = lane & 15;
    int f = fl * 8;

    uint4 ud = *(const uint4*)&fdb[(size_t)node * HID + f];
    float fdv[8] = { bflo(ud.x), bfhi(ud.x), bflo(ud.y), bfhi(ud.y),
                     bflo(ud.z), bfhi(ud.z), bflo(ud.w), bfhi(ud.w) };
    float4 aA = *(const float4*)&attn[f];
    float4 aB = *(const float4*)&attn[f + 4];
    float c1[8] = { 0.6f * aA.x, 0.6f * aA.y, 0.6f * aA.z, 0.6f * aA.w,
                    0.6f * aB.x, 0.6f * aB.y, 0.6f * aB.z, 0.6f * aB.w };
    float c2[8] = { 0.4f * aA.x, 0.4f * aA.y, 0.4f * aA.z, 0.4f * aA.w,
                    0.4f * aB.x, 0.4f * aB.y, 0.4f * aB.z, 0.4f * aB.w };

    int cnt = cursor[node * CSTR]; cnt = cnt < BKT ? cnt : BKT;
    const u16* brow = ebkt + (size_t)node * BKT;
    float acc[8] = {0.f, 0.f, 0.f, 0.f, 0.f, 0.f, 0.f, 0.f};
    float lsum = 0.f;

    auto loadrow = [&](int e) -> uint4 {
        int s = (int)brow[e];
        return *(const uint4*)&fsb[(size_t)s * HID + f];
    };
    auto compute = [&](uint4 u) {
        float x[8] = { bflo(u.x), bfhi(u.x), bflo(u.y), bfhi(u.y),
                       bflo(u.z), bfhi(u.z), bflo(u.w), bfhi(u.w) };
        float p = 0.f;
        #pragma unroll
        for (int i = 0; i < 8; i++) {
            float ei = x[i] + fdv[i];
            p = fmaf(c1[i], ei, p);
            p = fmaf(c2[i], fabsf(ei), p);    // fabs folds into fma src modifier
        }
        // head logit: sum over the 4 lanes of this head's quad
        p += __shfl_xor(p, 1); p += __shfl_xor(p, 2);
        float w = __expf(p);
        lsum += w;
        #pragma unroll
        for (int i = 0; i < 8; i++) acc[i] = fmaf(w, x[i], acc[i]);
    };

    // pipelined loop: groups handle edges e = grp, grp+4, grp+8, ...
    {
        int e = grp;
        uint4 bufA, bufB;
        bool vA = (e < cnt), vB = (e + 4 < cnt);
        if (vA) bufA = loadrow(e);
        if (vB) bufB = loadrow(e + 4);
        while (vA) {
            int en = e + 8;
            uint4 bufC; bool vC = (en < cnt);
            if (vC) bufC = loadrow(en);
            compute(bufA);
            bufA = bufB; vA = vB;
            bufB = bufC; vB = vC;
            e += 4;
        }
    }

    // merge the 4 edge-groups (same features, same head per quad)
    #pragma unroll
    for (int i = 0; i < 8; i++) {
        acc[i] += __shfl_xor(acc[i], 16);
        acc[i] += __shfl_xor(acc[i], 32);
    }
    lsum += __shfl_xor(lsum, 16); lsum += __shfl_xor(lsum, 32);

    float inv = (lsum > 0.f) ? (1.0f / lsum) : 0.f;
    float4 h0 = *(const float4*)&h[(size_t)node * HID + f];
    float4 h1v = *(const float4*)&h[(size_t)node * HID + f + 4];
    float hx[8] = { h0.x, h0.y, h0.z, h0.w, h1v.x, h1v.y, h1v.z, h1v.w };
    float o[8], s1 = 0.f, s2 = 0.f;
    #pragma unroll
    for (int i = 0; i < 8; i++) {
        o[i] = hx[i] + acc[i] * inv;
        s1 += o[i]; s2 += o[i] * o[i];
    }
    s1 += __shfl_xor(s1, 1); s2 += __shfl_xor(s2, 1);
    s1 += __shfl_xor(s1, 2); s2 += __shfl_xor(s2, 2);
    s1 += __shfl_xor(s1, 4); s2 += __shfl_xor(s2, 4);
    s1 += __shfl_xor(s1, 8); s2 += __shfl_xor(s2, 8);
    float mu = s1 * (1.0f / HID);
    float var = s2 * (1.0f / HID) - mu * mu;
    float rs = rsqrtf(var + LN_EPS);
    if (grp == 0) {
        float4 gA = *(const float4*)&g1[f], gB = *(const float4*)&g1[f + 4];
        float4 bA = *(const float4*)&beta1[f], bB = *(const float4*)&beta1[f + 4];
        float q0 = (o[0] - mu) * rs * gA.x + bA.x, q1 = (o[1] - mu) * rs * gA.y + bA.y;
        float q2 = (o[2] - mu) * rs * gA.z + bA.z, q3 = (o[3] - mu) * rs * gA.w + bA.w;
        float q4 = (o[4] - mu) * rs * gB.x + bB.x, q5 = (o[5] - mu) * rs * gB.y + bB.y;
        float q6 = (o[6] - mu) * rs * gB.z + bB.z, q7 = (o[7] - mu) * rs * gB.w + bB.w;
        uint4 ob;
        ob.x = packbf(q0, q1); ob.y = packbf(q2, q3);
        ob.z = packbf(q4, q5); ob.w = packbf(q6, q7);
        *(uint4*)&h1b[(size_t)node * HID + f] = ob;
    }
}

// ---------------- fused FFN: out = LN(h1 + gelu(h1@W1+bf1)@W2 + bf2) ----------------
// R3-proven M=16 structure at 640 blocks; A-operand AND residual from bf16 h1b.

#define TS_PAD 8   // +8 u16 = 16B: breaks 512B-stride bank pattern on phase-2 ds_read_b128

__global__ __launch_bounds__(256) void ffn_fused(
    const u16* __restrict__ h1b,
    const u16* __restrict__ B2sw, const u16* __restrict__ B3sw,
    const float* __restrict__ bf1, const float* __restrict__ bf2,
    const float* __restrict__ g2, const float* __restrict__ beta2,
    float* __restrict__ out)
{
    __shared__ u16 ts[16][FFN_HID + TS_PAD];
    __shared__ float xs[16][HID];
    int tid = threadIdx.x, wave = tid >> 6, lane = tid & 63;
    int lrow = lane & 15, lq = lane >> 4;

    short8 b1f[4][4];
    #pragma unroll
    for (int nt = 0; nt < 4; nt++)
        #pragma unroll
        for (int ks = 0; ks < 4; ks++) {
            int frag = (wave * 4 + nt) * 4 + ks;
            b1f[nt][ks] = *(const short8*)(B2sw + ((size_t)frag * 64 + lane) * 8);
        }
    short8 b2f[2][8];
    #pragma unroll
    for (int nt = 0; nt < 2; nt++)
        #pragma unroll
        for (int ks = 0; ks < 8; ks++) {
            int frag = (wave * 2 + nt) * 8 + ks;
            b2f[nt][ks] = *(const short8*)(B3sw + ((size_t)frag * 64 + lane) * 8);
        }
    float bias1[4];
    #pragma unroll
    for (int nt = 0; nt < 4; nt++) bias1[nt] = bf1[wave * 64 + nt * 16 + lrow];
    float bias2[2];
    #pragma unroll
    for (int nt = 0; nt < 2; nt++) bias2[nt] = bf2[wave * 32 + nt * 16 + lrow];

    for (int mb = blockIdx.x; mb < N_NODES / 16; mb += gridDim.x) {
        int m0 = mb * 16;
        // ---- phase 1: t = gelu(h1 @ W1 + bf1) into LDS ----
        floatx4 acc1[4];
        #pragma unroll
        for (int nt = 0; nt < 4; nt++) acc1[nt] = {0.f, 0.f, 0.f, 0.f};
        #pragma unroll
        for (int ks = 0; ks < 4; ks++) {
            short8 a = *(const short8*)(h1b + (size_t)(m0 + lrow) * HID + ks * 32 + lq * 8);
            #pragma unroll
            for (int nt = 0; nt < 4; nt++)
                acc1[nt] = __builtin_amdgcn_mfma_f32_16x16x32_bf16(a, b1f[nt][ks], acc1[nt], 0, 0, 0);
        }
        #pragma unroll
        for (int nt = 0; nt < 4; nt++) {
            int cg = wave * 64 + nt * 16 + lrow;
            #pragma unroll
            for (int r = 0; r < 4; r++) {
                float v = acc1[nt][r] + bias1[nt];
                ts[lq * 4 + r][cg] = f2bf(gelu_fast(v));
            }
        }
        __syncthreads();
        // ---- phase 2: x = t @ W2 + bf2 + h1 (residual from bf16 h1b) ----
        floatx4 acc2[2];
        #pragma unroll
        for (int nt = 0; nt < 2; nt++) acc2[nt] = {0.f, 0.f, 0.f, 0.f};
        #pragma unroll
        for (int ks = 0; ks < 8; ks++) {
            short8 a = *(const short8*)&ts[lrow][ks * 32 + lq * 8];
            #pragma unroll
            for (int nt = 0; nt < 2; nt++)
                acc2[nt] = __builtin_amdgcn_mfma_f32_16x16x32_bf16(a, b2f[nt][ks], acc2[nt], 0, 0, 0);
        }
        #pragma unroll
        for (int nt = 0; nt < 2; nt++) {
            int cg = wave * 32 + nt * 16 + lrow;
            #pragma unroll
            for (int r = 0; r < 4; r++) {
                int row = m0 + lq * 4 + r;
                float resid = bf2f(h1b[(size_t)row * HID + cg]);
                xs[lq * 4 + r][cg] = acc2[nt][r] + bias2[nt] + resid;
            }
        }
        __syncthreads();
        // ---- LN + store ----
        int row = tid >> 4, c0 = (tid & 15) * 8;
        float v[8];
        float s1 = 0.f, s2 = 0.f;
        #pragma unroll
        for (int i = 0; i < 8; i++) { v[i] = xs[row][c0 + i]; s1 += v[i]; s2 += v[i] * v[i]; }
        s1 += __shfl_xor(s1, 1); s2 += __shfl_xor(s2, 1);
        s1 += __shfl_xor(s1, 2); s2 += __shfl_xor(s2, 2);
        s1 += __shfl_xor(s1, 4); s2 += __shfl_xor(s2, 4);
        s1 += __shfl_xor(s1, 8); s2 += __shfl_xor(s2, 8);
        float mu = s1 * (1.0f / HID);
        float var = s2 * (1.0f / HID) - mu * mu;
        float rs = rsqrtf(var + LN_EPS);
        float o[8];
        #pragma unroll
        for (int i = 0; i < 8; i++) o[i] = (v[i] - mu) * rs * g2[c0 + i] + beta2[c0 + i];
        float* op = out + (size_t)(m0 + row) * HID + c0;
        *(float4*)(op)     = make_float4(o[0], o[1], o[2], o[3]);
        *(float4*)(op + 4) = make_float4(o[4], o[5], o[6], o[7]);
        __syncthreads();
    }
}

// ---------------- launch ----------------

extern "C" void kernel_launch(void* const* d_in, const int* in_sizes, int n_in,
                              void* d_out, int out_size, void* d_ws, size_t ws_size,
                              hipStream_t stream)
{
    const float* h    = (const float*)d_in[0];
    const int*   src  = (const int*)d_in[1];
    const int*   dst  = (const int*)d_in[2];
    const float* Wsrc = (const float*)d_in[3];
    const float* bsrc = (const float*)d_in[4];
    const float* Wdst = (const float*)d_in[5];
    const float* bdst = (const float*)d_in[6];
    const float* attn = (const float*)d_in[7];
    const float* W1   = (const float*)d_in[8];
    const float* bf1  = (const float*)d_in[9];
    const float* W2   = (const float*)d_in[10];
    const float* bf2  = (const float*)d_in[11];
    const float* g1   = (const float*)d_in[12];
    const float* beta1= (const float*)d_in[13];
    const float* g2   = (const float*)d_in[14];
    const float* beta2= (const float*)d_in[15];
    float* out = (float*)d_out;

    // workspace: fsb/fdb/h1b bf16 (12.8MB each), B1/B2/B3 (64KB each),
    // cursor (3.2MB, 64B-strided counters), ebkt u16 (6.4MB). ~49MB total.
    u16* fsb = (u16*)d_ws;
    u16* fdb = fsb + (size_t)N_NODES * HID;
    u16* h1b = fdb + (size_t)N_NODES * HID;
    u16* B1 = h1b + (size_t)N_NODES * HID;
    u16* B2 = B1 + 32768;
    u16* B3 = B2 + 32768;
    int* cursor = (int*)(B3 + 32768);
    u16* ebkt   = (u16*)(cursor + (size_t)N_NODES * CSTR);

    prep_kernel<<<384 + 3125, 256, 0, stream>>>(Wsrc, Wdst, W1, W2, B1, B2, B3, cursor);
    scatter_gemm<<<3368, 256, 0, stream>>>(src, dst, cursor, ebkt,
                                           h, B1, bsrc, bdst, fsb, fdb);
    aggregate_kernel<<<(N_NODES + 3) / 4, 256, 0, stream>>>(fsb, fdb, h, attn, cursor, ebkt, g1, beta1, h1b);
    ffn_fused<<<640, 256, 0, stream>>>(h1b, B2, B3, bf1, bf2, g2, beta2, out);
}

// Round 9
// 221.016 us; speedup vs baseline: 1.1706x; 1.0025x over previous
//
#include <hip/hip_runtime.h>
#include <math.h>

#define N_NODES 50000
#define N_EDGES 600000
#define HID 128
#define FFN_HID 256
#define NEG_SLOPE 0.2f
#define LN_EPS 1e-5f
#define BKT 64            // bucket capacity per node; max degree ~30 for E/N=12 Poisson
#define CSTR 16           // cursor stride (ints): one counter per 64B line

typedef unsigned short u16;
typedef unsigned int u32;
typedef __attribute__((ext_vector_type(8))) short short8;
typedef __attribute__((ext_vector_type(4))) float floatx4;

__device__ __forceinline__ u16 f2bf(float x) {
    unsigned int u = __float_as_uint(x);
    unsigned int r = u + 0x7FFFu + ((u >> 16) & 1u);
    return (u16)(r >> 16);
}
__device__ __forceinline__ float bflo(u32 u) { return __uint_as_float(u << 16); }
__device__ __forceinline__ float bfhi(u32 u) { return __uint_as_float(u & 0xffff0000u); }
__device__ __forceinline__ u32 packbf(float lo, float hi) {
    return (u32)f2bf(lo) | ((u32)f2bf(hi) << 16);
}
__device__ __forceinline__ float bf2f(u16 v) { return __uint_as_float(((u32)v) << 16); }
// tanh-form GELU: max |delta| vs exact erf-GELU ~3e-4; output is bf16-rounded anyway.
__device__ __forceinline__ float gelu_fast(float v) {
    float u = 1.5957691216057308f * fmaf(0.044715f * v * v, v, v);
    return v / (1.0f + __expf(-u));
}

// ---------------- co-launched (INTERLEAVED): edge bucket scatter + GEMM1 ----------
// grid = 1610 blocks. gemm role (1024): bid<1536 && bid%3!=2, gid=(bid/3)*2+(bid%3).
// scatter role (586): bid%3==2 -> sid=bid/3; bid>=1536 -> sid=512+(bid-1536).
// Scatter: 4 edges/thread (uint4 src/dst loads) -> 4 independent atomic chains
// in flight per thread. Gemm: B-fragments loaded DIRECTLY from raw Wsrc/Wdst
// with the inverse swizzle map (no prep kernel): for frag (wave*4+nt)*4+ks,
// lane, elem j:  ng = wave*64+nt*16+(lane&15), k = ks*32+(lane>>4)*8+j.

__global__ __launch_bounds__(256) void scatter_gemm(
    const int* __restrict__ src, const int* __restrict__ dst,
    int* __restrict__ cursor, u16* __restrict__ ebkt,
    const float* __restrict__ h,
    const float* __restrict__ Wsrc, const float* __restrict__ Wdst,
    const float* __restrict__ bsrc, const float* __restrict__ bdst,
    u16* __restrict__ fsb, u16* __restrict__ fdb)
{
    int bid = blockIdx.x;
    bool isGemm = (bid < 1536) && ((bid % 3) != 2);
    if (!isGemm) {
        int sid = (bid < 1536) ? (bid / 3) : (512 + bid - 1536);
        int t4 = sid * 256 + threadIdx.x;
        if (t4 < N_EDGES / 4) {
            uint4 d4 = *(const uint4*)&dst[t4 * 4];
            uint4 s4 = *(const uint4*)&src[t4 * 4];
            int slot0 = atomicAdd(&cursor[(int)d4.x * CSTR], 1);
            int slot1 = atomicAdd(&cursor[(int)d4.y * CSTR], 1);
            int slot2 = atomicAdd(&cursor[(int)d4.z * CSTR], 1);
            int slot3 = atomicAdd(&cursor[(int)d4.w * CSTR], 1);
            if (slot0 < BKT) ebkt[(size_t)d4.x * BKT + slot0] = (u16)s4.x;
            if (slot1 < BKT) ebkt[(size_t)d4.y * BKT + slot1] = (u16)s4.y;
            if (slot2 < BKT) ebkt[(size_t)d4.z * BKT + slot2] = (u16)s4.z;
            if (slot3 < BKT) ebkt[(size_t)d4.w * BKT + slot3] = (u16)s4.w;
        }
        return;
    }
    int gid = (bid / 3) * 2 + (bid % 3);
    int tid = threadIdx.x, wave = tid >> 6, lane = tid & 63;
    int lrow = lane & 15, lq = lane >> 4;
    // self-swizzled B fragments from raw W (one-time, L2-resident weights)
    short8 bfrag[4][4];
    float bias[4];
    #pragma unroll
    for (int nt = 0; nt < 4; nt++) {
        int cg = wave * 64 + nt * 16 + lrow;
        const float* Wp = (cg < HID) ? (Wsrc + cg) : (Wdst + cg - HID);
        bias[nt] = (cg < HID) ? bsrc[cg] : bdst[cg - HID];
        #pragma unroll
        for (int ks = 0; ks < 4; ks++) {
            short8 b;
            #pragma unroll
            for (int j = 0; j < 8; j++)
                b[j] = (short)f2bf(Wp[(size_t)(ks * 32 + lq * 8 + j) * HID]);
            bfrag[nt][ks] = b;
        }
    }
    for (int mb = gid; mb < N_NODES / 16; mb += 1024) {
        int m0 = mb * 16;
        const float* hrow = h + (size_t)(m0 + lrow) * HID;
        floatx4 acc[4];
        #pragma unroll
        for (int nt = 0; nt < 4; nt++) acc[nt] = {0.f, 0.f, 0.f, 0.f};
        #pragma unroll
        for (int ks = 0; ks < 4; ks++) {
            float4 va = *(const float4*)(hrow + ks * 32 + lq * 8);
            float4 vb = *(const float4*)(hrow + ks * 32 + lq * 8 + 4);
            short8 a;
            a[0] = (short)f2bf(va.x); a[1] = (short)f2bf(va.y);
            a[2] = (short)f2bf(va.z); a[3] = (short)f2bf(va.w);
            a[4] = (short)f2bf(vb.x); a[5] = (short)f2bf(vb.y);
            a[6] = (short)f2bf(vb.z); a[7] = (short)f2bf(vb.w);
            #pragma unroll
            for (int nt = 0; nt < 4; nt++)
                acc[nt] = __builtin_amdgcn_mfma_f32_16x16x32_bf16(a, bfrag[nt][ks], acc[nt], 0, 0, 0);
        }
        #pragma unroll
        for (int nt = 0; nt < 4; nt++) {
            int cg = wave * 64 + nt * 16 + lrow;      // wave-uniform branch per (wave,nt)
            u16* outp = (cg < HID) ? fsb : fdb;
            int c = cg & (HID - 1);
            #pragma unroll
            for (int r = 0; r < 4; r++) {
                int row = m0 + lq * 4 + r;
                outp[(size_t)row * HID + c] = f2bf(acc[nt][r] + bias[nt]);
            }
        }
    }
}

// ---------------- aggregation + residual + LN1 ----------------
// fs, fd gathered/streamed bf16; h residual f32. Emits h1 ONCE as bf16.
// Gather loop software-pipelined (3-buffer rotation, depth-2 prefetch).

__global__ __launch_bounds__(256) void aggregate_kernel(
    const u16* __restrict__ fsb, const u16* __restrict__ fdb,
    const float* __restrict__ h, const float* __restrict__ attn,
    const int* __restrict__ cursor, const u16* __restrict__ ebkt,
    const float* __restrict__ g1, const float* __restrict__ beta1,
    u16* __restrict__ h1b)
{
    int wave = threadIdx.x >> 6, lane = threadIdx.x & 63;
    int node = blockIdx.x * 4 + wave;
    if (node >= N_NODES) return;
    int grp = lane >> 4, fl = lane & 15;
    int f = fl * 8;

    uint4 ud = *(const uint4*)&fdb[(size_t)node * HID + f];
    float fdv[8] = { bflo(ud.x), bfhi(ud.x), bflo(ud.y), bfhi(ud.y),
                     bflo(ud.z), bfhi(ud.z), bflo(ud.w), bfhi(ud.w) };
    float4 aA = *(const float4*)&attn[f];
    float4 aB = *(const float4*)&attn[f + 4];
    float c1[8] = { 0.6f * aA.x, 0.6f * aA.y, 0.6f * aA.z, 0.6f * aA.w,
                    0.6f * aB.x, 0.6f * aB.y, 0.6f * aB.z, 0.6f * aB.w };
    float c2[8] = { 0.4f * aA.x, 0.4f * aA.y, 0.4f * aA.z, 0.4f * aA.w,
                    0.4f * aB.x, 0.4f * aB.y, 0.4f * aB.z, 0.4f * aB.w };

    int cnt = cursor[node * CSTR]; cnt = cnt < BKT ? cnt : BKT;
    const u16* brow = ebkt + (size_t)node * BKT;
    float acc[8] = {0.f, 0.f, 0.f, 0.f, 0.f, 0.f, 0.f, 0.f};
    float lsum = 0.f;

    auto loadrow = [&](int e) -> uint4 {
        int s = (int)brow[e];
        return *(const uint4*)&fsb[(size_t)s * HID + f];
    };
    auto compute = [&](uint4 u) {
        float x[8] = { bflo(u.x), bfhi(u.x), bflo(u.y), bfhi(u.y),
                       bflo(u.z), bfhi(u.z), bflo(u.w), bfhi(u.w) };
        float p = 0.f;
        #pragma unroll
        for (int i = 0; i < 8; i++) {
            float ei = x[i] + fdv[i];
            p = fmaf(c1[i], ei, p);
            p = fmaf(c2[i], fabsf(ei), p);    // fabs folds into fma src modifier
        }
        // head logit: sum over the 4 lanes of this head's quad
        p += __shfl_xor(p, 1); p += __shfl_xor(p, 2);
        float w = __expf(p);
        lsum += w;
        #pragma unroll
        for (int i = 0; i < 8; i++) acc[i] = fmaf(w, x[i], acc[i]);
    };

    // pipelined loop: groups handle edges e = grp, grp+4, grp+8, ...
    {
        int e = grp;
        uint4 bufA, bufB;
        bool vA = (e < cnt), vB = (e + 4 < cnt);
        if (vA) bufA = loadrow(e);
        if (vB) bufB = loadrow(e + 4);
        while (vA) {
            int en = e + 8;
            uint4 bufC; bool vC = (en < cnt);
            if (vC) bufC = loadrow(en);
            compute(bufA);
            bufA = bufB; vA = vB;
            bufB = bufC; vB = vC;
            e += 4;
        }
    }

    // merge the 4 edge-groups (same features, same head per quad)
    #pragma unroll
    for (int i = 0; i < 8; i++) {
        acc[i] += __shfl_xor(acc[i], 16);
        acc[i] += __shfl_xor(acc[i], 32);
    }
    lsum += __shfl_xor(lsum, 16); lsum += __shfl_xor(lsum, 32);

    float inv = (lsum > 0.f) ? (1.0f / lsum) : 0.f;
    float4 h0 = *(const float4*)&h[(size_t)node * HID + f];
    float4 h1v = *(const float4*)&h[(size_t)node * HID + f + 4];
    float hx[8] = { h0.x, h0.y, h0.z, h0.w, h1v.x, h1v.y, h1v.z, h1v.w };
    float o[8], s1 = 0.f, s2 = 0.f;
    #pragma unroll
    for (int i = 0; i < 8; i++) {
        o[i] = hx[i] + acc[i] * inv;
        s1 += o[i]; s2 += o[i] * o[i];
    }
    s1 += __shfl_xor(s1, 1); s2 += __shfl_xor(s2, 1);
    s1 += __shfl_xor(s1, 2); s2 += __shfl_xor(s2, 2);
    s1 += __shfl_xor(s1, 4); s2 += __shfl_xor(s2, 4);
    s1 += __shfl_xor(s1, 8); s2 += __shfl_xor(s2, 8);
    float mu = s1 * (1.0f / HID);
    float var = s2 * (1.0f / HID) - mu * mu;
    float rs = rsqrtf(var + LN_EPS);
    if (grp == 0) {
        float4 gA = *(const float4*)&g1[f], gB = *(const float4*)&g1[f + 4];
        float4 bA = *(const float4*)&beta1[f], bB = *(const float4*)&beta1[f + 4];
        float q0 = (o[0] - mu) * rs * gA.x + bA.x, q1 = (o[1] - mu) * rs * gA.y + bA.y;
        float q2 = (o[2] - mu) * rs * gA.z + bA.z, q3 = (o[3] - mu) * rs * gA.w + bA.w;
        float q4 = (o[4] - mu) * rs * gB.x + bB.x, q5 = (o[5] - mu) * rs * gB.y + bB.y;
        float q6 = (o[6] - mu) * rs * gB.z + bB.z, q7 = (o[7] - mu) * rs * gB.w + bB.w;
        uint4 ob;
        ob.x = packbf(q0, q1); ob.y = packbf(q2, q3);
        ob.z = packbf(q4, q5); ob.w = packbf(q6, q7);
        *(uint4*)&h1b[(size_t)node * HID + f] = ob;
    }
}

// ---------------- fused FFN: out = LN(h1 + gelu(h1@W1+bf1)@W2 + bf2) ----------------
// M=16 structure at 640 blocks; A-operand AND residual from bf16 h1b.
// B-fragments self-swizzled from raw W1/W2 (inverse map, L2-resident).

#define TS_PAD 8   // +8 u16 = 16B: breaks 512B-stride bank pattern on phase-2 ds_read_b128

__global__ __launch_bounds__(256) void ffn_fused(
    const u16* __restrict__ h1b,
    const float* __restrict__ W1, const float* __restrict__ W2,
    const float* __restrict__ bf1, const float* __restrict__ bf2,
    const float* __restrict__ g2, const float* __restrict__ beta2,
    float* __restrict__ out)
{
    __shared__ u16 ts[16][FFN_HID + TS_PAD];
    __shared__ float xs[16][HID];
    int tid = threadIdx.x, wave = tid >> 6, lane = tid & 63;
    int lrow = lane & 15, lq = lane >> 4;

    // b1f[nt][ks][j] = W1[(ks*32+lq*8+j)*256 + (wave*64+nt*16+lrow)]
    short8 b1f[4][4];
    #pragma unroll
    for (int nt = 0; nt < 4; nt++) {
        int cg = wave * 64 + nt * 16 + lrow;
        #pragma unroll
        for (int ks = 0; ks < 4; ks++) {
            short8 b;
            #pragma unroll
            for (int j = 0; j < 8; j++)
                b[j] = (short)f2bf(W1[(size_t)(ks * 32 + lq * 8 + j) * FFN_HID + cg]);
            b1f[nt][ks] = b;
        }
    }
    // b2f[nt][ks][j] = W2[(ks*32+lq*8+j)*128 + (wave*32+nt*16+lrow)]
    short8 b2f[2][8];
    #pragma unroll
    for (int nt = 0; nt < 2; nt++) {
        int cg = wave * 32 + nt * 16 + lrow;
        #pragma unroll
        for (int ks = 0; ks < 8; ks++) {
            short8 b;
            #pragma unroll
            for (int j = 0; j < 8; j++)
                b[j] = (short)f2bf(W2[(size_t)(ks * 32 + lq * 8 + j) * HID + cg]);
            b2f[nt][ks] = b;
        }
    }
    float bias1[4];
    #pragma unroll
    for (int nt = 0; nt < 4; nt++) bias1[nt] = bf1[wave * 64 + nt * 16 + lrow];
    float bias2[2];
    #pragma unroll
    for (int nt = 0; nt < 2; nt++) bias2[nt] = bf2[wave * 32 + nt * 16 + lrow];

    for (int mb = blockIdx.x; mb < N_NODES / 16; mb += gridDim.x) {
        int m0 = mb * 16;
        // ---- phase 1: t = gelu(h1 @ W1 + bf1) into LDS ----
        floatx4 acc1[4];
        #pragma unroll
        for (int nt = 0; nt < 4; nt++) acc1[nt] = {0.f, 0.f, 0.f, 0.f};
        #pragma unroll
        for (int ks = 0; ks < 4; ks++) {
            short8 a = *(const short8*)(h1b + (size_t)(m0 + lrow) * HID + ks * 32 + lq * 8);
            #pragma unroll
            for (int nt = 0; nt < 4; nt++)
                acc1[nt] = __builtin_amdgcn_mfma_f32_16x16x32_bf16(a, b1f[nt][ks], acc1[nt], 0, 0, 0);
        }
        #pragma unroll
        for (int nt = 0; nt < 4; nt++) {
            int cg = wave * 64 + nt * 16 + lrow;
            #pragma unroll
            for (int r = 0; r < 4; r++) {
                float v = acc1[nt][r] + bias1[nt];
                ts[lq * 4 + r][cg] = f2bf(gelu_fast(v));
            }
        }
        __syncthreads();
        // ---- phase 2: x = t @ W2 + bf2 + h1 (residual from bf16 h1b) ----
        floatx4 acc2[2];
        #pragma unroll
        for (int nt = 0; nt < 2; nt++) acc2[nt] = {0.f, 0.f, 0.f, 0.f};
        #pragma unroll
        for (int ks = 0; ks < 8; ks++) {
            short8 a = *(const short8*)&ts[lrow][ks * 32 + lq * 8];
            #pragma unroll
            for (int nt = 0; nt < 2; nt++)
                acc2[nt] = __builtin_amdgcn_mfma_f32_16x16x32_bf16(a, b2f[nt][ks], acc2[nt], 0, 0, 0);
        }
        #pragma unroll
        for (int nt = 0; nt < 2; nt++) {
            int cg = wave * 32 + nt * 16 + lrow;
            #pragma unroll
            for (int r = 0; r < 4; r++) {
                int row = m0 + lq * 4 + r;
                float resid = bf2f(h1b[(size_t)row * HID + cg]);
                xs[lq * 4 + r][cg] = acc2[nt][r] + bias2[nt] + resid;
            }
        }
        __syncthreads();
        // ---- LN + store ----
        int row = tid >> 4, c0 = (tid & 15) * 8;
        float v[8];
        float s1 = 0.f, s2 = 0.f;
        #pragma unroll
        for (int i = 0; i < 8; i++) { v[i] = xs[row][c0 + i]; s1 += v[i]; s2 += v[i] * v[i]; }
        s1 += __shfl_xor(s1, 1); s2 += __shfl_xor(s2, 1);
        s1 += __shfl_xor(s1, 2); s2 += __shfl_xor(s2, 2);
        s1 += __shfl_xor(s1, 4); s2 += __shfl_xor(s2, 4);
        s1 += __shfl_xor(s1, 8); s2 += __shfl_xor(s2, 8);
        float mu = s1 * (1.0f / HID);
        float var = s2 * (1.0f / HID) - mu * mu;
        float rs = rsqrtf(var + LN_EPS);
        float o[8];
        #pragma unroll
        for (int i = 0; i < 8; i++) o[i] = (v[i] - mu) * rs * g2[c0 + i] + beta2[c0 + i];
        float* op = out + (size_t)(m0 + row) * HID + c0;
        *(float4*)(op)     = make_float4(o[0], o[1], o[2], o[3]);
        *(float4*)(op + 4) = make_float4(o[4], o[5], o[6], o[7]);
        __syncthreads();
    }
}

// ---------------- launch ----------------

extern "C" void kernel_launch(void* const* d_in, const int* in_sizes, int n_in,
                              void* d_out, int out_size, void* d_ws, size_t ws_size,
                              hipStream_t stream)
{
    const float* h    = (const float*)d_in[0];
    const int*   src  = (const int*)d_in[1];
    const int*   dst  = (const int*)d_in[2];
    const float* Wsrc = (const float*)d_in[3];
    const float* bsrc = (const float*)d_in[4];
    const float* Wdst = (const float*)d_in[5];
    const float* bdst = (const float*)d_in[6];
    const float* attn = (const float*)d_in[7];
    const float* W1   = (const float*)d_in[8];
    const float* bf1  = (const float*)d_in[9];
    const float* W2   = (const float*)d_in[10];
    const float* bf2  = (const float*)d_in[11];
    const float* g1   = (const float*)d_in[12];
    const float* beta1= (const float*)d_in[13];
    const float* g2   = (const float*)d_in[14];
    const float* beta2= (const float*)d_in[15];
    float* out = (float*)d_out;

    // workspace: fsb/fdb/h1b bf16 (12.8MB each), cursor (3.2MB, 64B-strided),
    // ebkt u16 (6.4MB). ~48MB total.
    u16* fsb = (u16*)d_ws;
    u16* fdb = fsb + (size_t)N_NODES * HID;
    u16* h1b = fdb + (size_t)N_NODES * HID;
    int* cursor = (int*)(h1b + (size_t)N_NODES * HID);
    u16* ebkt   = (u16*)(cursor + (size_t)N_NODES * CSTR);

    hipMemsetAsync(cursor, 0, (size_t)N_NODES * CSTR * sizeof(int), stream);
    scatter_gemm<<<1610, 256, 0, stream>>>(src, dst, cursor, ebkt,
                                           h, Wsrc, Wdst, bsrc, bdst, fsb, fdb);
    aggregate_kernel<<<(N_NODES + 3) / 4, 256, 0, stream>>>(fsb, fdb, h, attn, cursor, ebkt, g1, beta1, h1b);
    ffn_fused<<<640, 256, 0, stream>>>(h1b, W1, W2, bf1, bf2, g2, beta2, out);
}